// Round 11
// baseline (1713.779 us; speedup 1.0000x reference)
//
#include <hip/hip_runtime.h>
#include <hip/hip_bf16.h>
#include <math.h>

#define N_NODES 50000
#define NPAD    50048            // 391 * 128
#define N_EDGES 300000
#define IN_DIM  128
#define C       256
#define LAYERS  6
#define N_GRAPHS 256
#define SCAN_B  49               // ceil(N_NODES / 1024)

typedef __attribute__((ext_vector_type(8))) short v8s;
typedef __attribute__((ext_vector_type(4))) float v4f;

__device__ __forceinline__ unsigned short f2b(float f) {   // fp32 -> bf16 RNE
    unsigned int u = __float_as_uint(f);
    unsigned int r = (u + 0x7FFFu + ((u >> 16) & 1u)) >> 16;
    return (unsigned short)r;
}
__device__ __forceinline__ float b2f(unsigned short b) {
    return __uint_as_float(((unsigned int)b) << 16);
}

// async global->LDS, 16B per lane. LDS dest must be linear (base + lane*16);
// per-lane GLOBAL source is allowed -> swizzle lives on the source side.
__device__ __forceinline__ void gload16(const unsigned short* g, unsigned short* l) {
    __builtin_amdgcn_global_load_lds(
        (const __attribute__((address_space(1))) unsigned int*)(const void*)g,
        (__attribute__((address_space(3))) unsigned int*)(void*)l, 16, 0, 0);
}

// ---------------------------------------------------------------------------
// CSR build: count -> hierarchical scan (A/B/C) -> fill
// ---------------------------------------------------------------------------
__global__ void count_kernel(const int* __restrict__ ei, int* __restrict__ deg) {
    int e = blockIdx.x * blockDim.x + threadIdx.x;
    if (e < N_EDGES) atomicAdd(&deg[ei[N_EDGES + e]], 1);
}

__global__ __launch_bounds__(1024) void scanA(const int* __restrict__ deg,
                                              int* __restrict__ pre,
                                              int* __restrict__ bsum) {
    __shared__ int buf[1024];
    int b = blockIdx.x, tid = threadIdx.x;
    int i = b * 1024 + tid;
    int v = (i < N_NODES) ? deg[i] : 0;
    buf[tid] = v;
    __syncthreads();
    for (int off = 1; off < 1024; off <<= 1) {
        int t = (tid >= off) ? buf[tid - off] : 0;
        __syncthreads();
        buf[tid] += t;
        __syncthreads();
    }
    if (i < N_NODES) pre[i] = buf[tid] - v;   // exclusive within block
    if (tid == 1023) bsum[b] = buf[1023];
}

__global__ void scanB(int* __restrict__ bsum) {
    if (threadIdx.x == 0 && blockIdx.x == 0) {
        int acc = 0;
        for (int b = 0; b < SCAN_B; ++b) { int t = bsum[b]; bsum[b] = acc; acc += t; }
    }
}

__global__ __launch_bounds__(256) void scanC(const int* __restrict__ pre,
                                             const int* __restrict__ bsum,
                                             int* __restrict__ row_ptr,
                                             int* __restrict__ cursor) {
    int i = blockIdx.x * 256 + threadIdx.x;
    if (i < N_NODES) {
        int v = pre[i] + bsum[i >> 10];
        row_ptr[i] = v;
        cursor[i] = v;
    }
    if (i == N_NODES) row_ptr[N_NODES] = N_EDGES;
}

__global__ void fill_kernel(const int* __restrict__ ei, int* __restrict__ cursor,
                            int* __restrict__ col_src) {
    int e = blockIdx.x * blockDim.x + threadIdx.x;
    if (e >= N_EDGES) return;
    int d = ei[N_EDGES + e];
    int pos = atomicAdd(&cursor[d], 1);
    col_src[pos] = ei[e];
}

// ---------------------------------------------------------------------------
// weight prep.
//  WH [768][256] = bf16(w_hh)
//  WS [6][768][256]: WS_l = w_l @ Wih^T fold (fp32 math)
// ---------------------------------------------------------------------------
__global__ __launch_bounds__(256) void conv_whh(const float* __restrict__ whh,
                                                unsigned short* __restrict__ WH) {
    int t = blockIdx.x * 256 + threadIdx.x;
    if (t < 768 * 256) WH[t] = f2b(whh[t]);
}

__global__ __launch_bounds__(256) void fuse_ws(const float* __restrict__ wih,
                                               const float* __restrict__ w,
                                               unsigned short* __restrict__ WS) {
    __shared__ float As[16][64];
    __shared__ float Bs[16][64];
    const int j0 = blockIdx.x * 64;
    const int k0 = blockIdx.y * 64;
    const int l  = blockIdx.z;
    const float* wl = w + (size_t)l * C * C;
    const int tid = threadIdx.x;
    const int ty = tid >> 4, tx = tid & 15;
    const int lrow = tid >> 2, lt4 = (tid & 3) * 4;
    float acc[4][4] = {};
    for (int t0 = 0; t0 < C; t0 += 16) {
        float4 a = *(const float4*)(wih + (size_t)(j0 + lrow) * C + t0 + lt4);
        As[lt4 + 0][lrow] = a.x; As[lt4 + 1][lrow] = a.y;
        As[lt4 + 2][lrow] = a.z; As[lt4 + 3][lrow] = a.w;
        float4 b = *(const float4*)(wl + (size_t)(k0 + lrow) * C + t0 + lt4);
        Bs[lt4 + 0][lrow] = b.x; Bs[lt4 + 1][lrow] = b.y;
        Bs[lt4 + 2][lrow] = b.z; Bs[lt4 + 3][lrow] = b.w;
        __syncthreads();
#pragma unroll
        for (int kk = 0; kk < 16; ++kk) {
            float af[4], bf[4];
#pragma unroll
            for (int i = 0; i < 4; i++) { af[i] = As[kk][ty * 4 + i]; bf[i] = Bs[kk][tx * 4 + i]; }
#pragma unroll
            for (int i = 0; i < 4; i++)
#pragma unroll
                for (int j = 0; j < 4; j++) acc[i][j] += af[i] * bf[j];
        }
        __syncthreads();
    }
    unsigned short* outp = WS + (size_t)l * 768 * C;
#pragma unroll
    for (int i = 0; i < 4; i++)
#pragma unroll
        for (int j = 0; j < 4; j++)
            outp[(size_t)(j0 + ty * 4 + i) * C + k0 + tx * 4 + j] = f2b(acc[i][j]);
}

// ---------------------------------------------------------------------------
// pad x [N,128] -> Hb bf16 [NPAD,256]
// ---------------------------------------------------------------------------
__global__ __launch_bounds__(256) void pad_kernel(const float* __restrict__ x,
                                                  unsigned short* __restrict__ Hb) {
    int t = blockIdx.x * 256 + threadIdx.x;
    int node = t >> 5, q = t & 31;
    if (node >= NPAD) return;
    v8s out = {0, 0, 0, 0, 0, 0, 0, 0};
    if (node < N_NODES && q < 16) {
        const float* xp = x + (size_t)node * IN_DIM + q * 8;
        float4 a = *(const float4*)xp;
        float4 b = *(const float4*)(xp + 4);
        out[0] = (short)f2b(a.x); out[1] = (short)f2b(a.y);
        out[2] = (short)f2b(a.z); out[3] = (short)f2b(a.w);
        out[4] = (short)f2b(b.x); out[5] = (short)f2b(b.y);
        out[6] = (short)f2b(b.z); out[7] = (short)f2b(b.w);
    }
    *(v8s*)(Hb + (size_t)node * C + q * 8) = out;
}

// ---------------------------------------------------------------------------
// S[d] = sum_{e: dst==d} h[src_e]  — 4-edge unroll (4 independent row loads)
// ---------------------------------------------------------------------------
__global__ __launch_bounds__(256) void gather_bf16(const unsigned short* __restrict__ Hb,
                                                   const int* __restrict__ row_ptr,
                                                   const int* __restrict__ col_src,
                                                   unsigned short* __restrict__ Sb) {
    int wave = threadIdx.x >> 6, lane = threadIdx.x & 63;
    int node = blockIdx.x * 4 + wave;
    if (node >= N_NODES) return;
    int beg = row_ptr[node], end = row_ptr[node + 1];
    float a0 = 0.f, a1 = 0.f, a2 = 0.f, a3 = 0.f;
    const unsigned short* hp = Hb + lane * 4;

    auto accum = [&](uint2 raw) {
        a0 += __uint_as_float((raw.x & 0xFFFFu) << 16);
        a1 += __uint_as_float(raw.x & 0xFFFF0000u);
        a2 += __uint_as_float((raw.y & 0xFFFFu) << 16);
        a3 += __uint_as_float(raw.y & 0xFFFF0000u);
    };

    int p = beg;
    for (; p + 4 <= end; p += 4) {
        int s0 = col_src[p + 0], s1 = col_src[p + 1];
        int s2 = col_src[p + 2], s3 = col_src[p + 3];
        uint2 r0 = *(const uint2*)(hp + (size_t)s0 * C);
        uint2 r1 = *(const uint2*)(hp + (size_t)s1 * C);
        uint2 r2 = *(const uint2*)(hp + (size_t)s2 * C);
        uint2 r3 = *(const uint2*)(hp + (size_t)s3 * C);
        accum(r0); accum(r1); accum(r2); accum(r3);
    }
    for (; p < end; ++p) {
        int s = col_src[p];
        accum(*(const uint2*)(hp + (size_t)s * C));
    }
    uint2 out;
    out.x = (unsigned int)f2b(a0) | ((unsigned int)f2b(a1) << 16);
    out.y = (unsigned int)f2b(a2) | ((unsigned int)f2b(a3) << 16);
    *(uint2*)(Sb + (size_t)node * C + lane * 4) = out;
}

// ---------------------------------------------------------------------------
// Fused GRU, LDS-staged double-buffer, counted vmcnt (T4) + XCD swizzle (T1)
// + XOR bank swizzle (T2). Round 11: __launch_bounds__(256,4) -> 4 blocks/CU
// co-resident (inter-block waves are not barrier-synced -> implicit overlap,
// m114 mechanism); T5 setprio(1) around the MFMA cluster (role diversity
// across blocks gives the scheduler something to arbitrate).
// ---------------------------------------------------------------------------
__global__ __launch_bounds__(256, 4) void gru_fused(const unsigned short* __restrict__ Sb,
                                                    const unsigned short* __restrict__ Hb,
                                                    const unsigned short* __restrict__ WS,
                                                    const unsigned short* __restrict__ WH,
                                                    const float* __restrict__ b_ih,
                                                    const float* __restrict__ b_hh,
                                                    unsigned short* __restrict__ Hout) {
    __shared__ unsigned short AsL[2][128 * 32];   // [buf][row*32 + k]   8KB each
    __shared__ unsigned short BsL[2][192 * 32];   // [buf][vrow*32 + k] 12KB each

    const int tid = threadIdx.x;
    const int lane = tid & 63, wid = tid >> 6;
    const int wr = wid >> 1, wc = wid & 1;        // wave grid 2x2

    // bijective XCD swizzle over 1564 blocks (8 XCDs; 1564 = 8*195 + 4).
    const int p = blockIdx.x;
    const int xcd = p & 7;
    const int q = 1564 >> 3, r8 = 1564 & 7;       // 195, 4
    const int base = (xcd < r8) ? xcd * (q + 1) : r8 * (q + 1) + (xcd - r8) * q;
    const int L = base + (p >> 3);
    const int gr0 = (L >> 2) * 128;               // 391 row-blocks
    const int c0 = (L & 3) * 64;                  // 4 col-blocks
    const int lr = lane & 15;

    // read-side swizzled chunk offset: phys = (lane>>4) ^ ((lr>>1)&3)
    const int kg = (((lane >> 4) ^ ((lr >> 1) & 3)) & 3) * 8;

    // staging: LDS dest linear (lane*16); global source chunk xor-swizzled
    const int srow = lane >> 2;
    const int schunk = (((lane & 3) ^ ((lane >> 3) & 3)) & 3) * 8;

    v4f aR[4][2] = {}, aZ[4][2] = {}, aNi[4][2] = {}, aNh[4][2] = {};

    auto stage = [&](int b, int t) {
        const bool lo2 = (t < 8);
        const unsigned short* Asrc = lo2 ? Sb : Hb;
        const unsigned short* Wsrc = lo2 ? WS : WH;
        const int kc = (t & 7) * 32;
        unsigned short* Ab = AsL[b];
        unsigned short* Bb = BsL[b];
#pragma unroll
        for (int ii = 0; ii < 2; ++ii) {
            int i = wid * 2 + ii;
            int row = i * 16 + srow;
            gload16(Asrc + (size_t)(gr0 + row) * C + kc + schunk,
                    Ab + row * 32 + (lane & 3) * 8);
        }
#pragma unroll
        for (int jj = 0; jj < 3; ++jj) {
            int j = wid * 3 + jj;
            int vrow = j * 16 + srow;
            int g = vrow >> 6, cc = vrow & 63;
            gload16(Wsrc + (size_t)(g * 256 + c0 + cc) * C + kc + schunk,
                    Bb + vrow * 32 + (lane & 3) * 8);
        }
    };

    auto compute = [&](int b, bool lo2) {
        const unsigned short* Ab = AsL[b];
        const unsigned short* Bb = BsL[b];
        v8s a[4], bR[2], bZ[2], bN[2];
#pragma unroll
        for (int fi = 0; fi < 4; fi++)
            a[fi] = *(const v8s*)(Ab + (wr * 64 + fi * 16 + lr) * 32 + kg);
#pragma unroll
        for (int fj = 0; fj < 2; fj++) {
            int brow = wc * 32 + fj * 16 + lr;
            bR[fj] = *(const v8s*)(Bb + brow * 32 + kg);
            bZ[fj] = *(const v8s*)(Bb + (brow + 64) * 32 + kg);
            bN[fj] = *(const v8s*)(Bb + (brow + 128) * 32 + kg);
        }
        __builtin_amdgcn_s_setprio(1);
#pragma unroll
        for (int fi = 0; fi < 4; fi++)
#pragma unroll
            for (int fj = 0; fj < 2; fj++) {
                aR[fi][fj] = __builtin_amdgcn_mfma_f32_16x16x32_bf16(a[fi], bR[fj], aR[fi][fj], 0, 0, 0);
                aZ[fi][fj] = __builtin_amdgcn_mfma_f32_16x16x32_bf16(a[fi], bZ[fj], aZ[fi][fj], 0, 0, 0);
                if (lo2)
                    aNi[fi][fj] = __builtin_amdgcn_mfma_f32_16x16x32_bf16(a[fi], bN[fj], aNi[fi][fj], 0, 0, 0);
                else
                    aNh[fi][fj] = __builtin_amdgcn_mfma_f32_16x16x32_bf16(a[fi], bN[fj], aNh[fi][fj], 0, 0, 0);
            }
        __builtin_amdgcn_s_setprio(0);
    };

    stage(0, 0);
#pragma unroll
    for (int t = 0; t < 16; ++t) {
        if (t < 15) {
            stage((t + 1) & 1, t + 1);     // +5 in flight (never drained below)
            asm volatile("s_waitcnt vmcnt(5)" ::: "memory");   // stage(t) done
        } else {
            asm volatile("s_waitcnt vmcnt(0)" ::: "memory");   // tail drain
        }
        __builtin_amdgcn_sched_barrier(0);
        __builtin_amdgcn_s_barrier();      // all waves: buf[t] fully written
        __builtin_amdgcn_sched_barrier(0);
        compute(t & 1, t < 8);             // plain LDS reads; compiler lgkmcnt
        __builtin_amdgcn_sched_barrier(0);
        __builtin_amdgcn_s_barrier();      // all waves done reading buf[t]
        __builtin_amdgcn_sched_barrier(0);
    }

    // ---- epilogue: gates in fp32 ----
    const int rbase = (lane >> 4) * 4;
#pragma unroll
    for (int fj = 0; fj < 2; fj++) {
        int col = c0 + wc * 32 + fj * 16 + lr;
        float brz_r = b_ih[col] + b_hh[col];
        float brz_z = b_ih[col + 256] + b_hh[col + 256];
        float bi_n = b_ih[col + 512];
        float bh_n = b_hh[col + 512];
#pragma unroll
        for (int fi = 0; fi < 4; fi++)
#pragma unroll
            for (int r = 0; r < 4; r++) {
                int row = gr0 + wr * 64 + fi * 16 + rbase + r;
                float hold = b2f(Hb[(size_t)row * C + col]);
                float rg = 1.f / (1.f + __expf(-(aR[fi][fj][r] + brz_r)));
                float z  = 1.f / (1.f + __expf(-(aZ[fi][fj][r] + brz_z)));
                float nn = tanhf(aNi[fi][fj][r] + bi_n + rg * (aNh[fi][fj][r] + bh_n));
                float outv = (1.f - z) * nn + z * hold;
                Hout[(size_t)row * C + col] = f2b(outv);
            }
    }
}

// ---------------------------------------------------------------------------
// mean pool + classifier
// ---------------------------------------------------------------------------
__global__ __launch_bounds__(256) void pool2(const unsigned short* __restrict__ Hb,
                                             const int* __restrict__ batch,
                                             float* __restrict__ g) {
    int b = blockIdx.x, j = threadIdx.x;
    __shared__ int bound[2];
    if (j < 2) {
        int target = b + j;
        int lo = 0, hi = N_NODES;
        while (lo < hi) {
            int mid = (lo + hi) >> 1;
            if (batch[mid] < target) lo = mid + 1; else hi = mid;
        }
        bound[j] = lo;
    }
    __syncthreads();
    int slo = bound[0], shi = bound[1];
    float a0 = 0.f, a1 = 0.f, a2 = 0.f, a3 = 0.f;
    int row = slo;
    for (; row + 3 < shi; row += 4) {
        a0 += b2f(Hb[(size_t)(row + 0) * C + j]);
        a1 += b2f(Hb[(size_t)(row + 1) * C + j]);
        a2 += b2f(Hb[(size_t)(row + 2) * C + j]);
        a3 += b2f(Hb[(size_t)(row + 3) * C + j]);
    }
    for (; row < shi; ++row) a0 += b2f(Hb[(size_t)row * C + j]);
    float acc = (a0 + a1) + (a2 + a3);
    float cnt = (float)(shi - slo);
    g[b * C + j] = acc / fmaxf(cnt, 1.f);
}

__global__ __launch_bounds__(128) void cls_kernel(const float* __restrict__ g,
                                                  const float* __restrict__ W1,
                                                  const float* __restrict__ b1,
                                                  const float* __restrict__ W2,
                                                  const float* __restrict__ b2,
                                                  float* __restrict__ out) {
    int b = blockIdx.x, j = threadIdx.x;
    float acc = b1[j];
    for (int k = 0; k < C; k += 4) {
        float4 gv = *(const float4*)(g + (size_t)b * C + k);
        float4 wv = *(const float4*)(W1 + (size_t)j * C + k);
        acc += gv.x * wv.x + gv.y * wv.y + gv.z * wv.z + gv.w * wv.w;
    }
    float hc = fmaxf(acc, 0.f);
    float v = W2[j] * hc;
    __shared__ float red[128];
    red[j] = v;
    __syncthreads();
    for (int s = 64; s > 0; s >>= 1) {
        if (j < s) red[j] += red[j + s];
        __syncthreads();
    }
    if (j == 0) out[b] = 1.f / (1.f + __expf(-(red[0] + b2[0])));
}

// ---------------------------------------------------------------------------
extern "C" void kernel_launch(void* const* d_in, const int* in_sizes, int n_in,
                              void* d_out, int out_size, void* d_ws, size_t ws_size,
                              hipStream_t stream) {
    const float* x      = (const float*)d_in[0];
    const int*   ei     = (const int*)d_in[1];
    const int*   batch  = (const int*)d_in[2];
    const float* weight = (const float*)d_in[3];
    const float* w_ih   = (const float*)d_in[4];
    const float* w_hh   = (const float*)d_in[5];
    const float* b_ih   = (const float*)d_in[6];
    const float* b_hh   = (const float*)d_in[7];
    const float* W1     = (const float*)d_in[8];
    const float* b1     = (const float*)d_in[9];
    const float* W2     = (const float*)d_in[10];
    const float* b2     = (const float*)d_in[11];
    float* out = (float*)d_out;

    char* ws = (char*)d_ws;
    size_t o = 0;
    auto alloc = [&](size_t bytes) {
        void* p = ws + o;
        o = (o + bytes + 255) & ~(size_t)255;
        return p;
    };
    unsigned short* HbA = (unsigned short*)alloc((size_t)NPAD * C * 2);
    unsigned short* HbB = (unsigned short*)alloc((size_t)NPAD * C * 2);
    unsigned short* Sb  = (unsigned short*)alloc((size_t)NPAD * C * 2);
    unsigned short* WSb = (unsigned short*)alloc((size_t)LAYERS * 768 * C * 2);
    unsigned short* WHb = (unsigned short*)alloc((size_t)768 * C * 2);
    float* g = (float*)alloc((size_t)N_GRAPHS * C * 4);
    int* deg     = (int*)alloc((size_t)N_NODES * 4);
    int* pre     = (int*)alloc((size_t)N_NODES * 4);
    int* bsum    = (int*)alloc((size_t)64 * 4);
    int* row_ptr = (int*)alloc((size_t)(N_NODES + 1) * 4);
    int* cursor  = (int*)alloc((size_t)N_NODES * 4);
    int* col_src = (int*)alloc((size_t)N_EDGES * 4);

    // weight prep + CSR build
    conv_whh<<<768, 256, 0, stream>>>(w_hh, WHb);
    fuse_ws<<<dim3(12, 4, 6), 256, 0, stream>>>(w_ih, weight, WSb);
    hipMemsetAsync(deg, 0, (size_t)N_NODES * 4, stream);
    count_kernel<<<(N_EDGES + 255) / 256, 256, 0, stream>>>(ei, deg);
    scanA<<<SCAN_B, 1024, 0, stream>>>(deg, pre, bsum);
    scanB<<<1, 64, 0, stream>>>(bsum);
    scanC<<<(N_NODES + 256) / 256, 256, 0, stream>>>(pre, bsum, row_ptr, cursor);
    fill_kernel<<<(N_EDGES + 255) / 256, 256, 0, stream>>>(ei, cursor, col_src);

    // h0 = pad(x) -> bf16
    pad_kernel<<<(NPAD * 32) / 256, 256, 0, stream>>>(x, HbA);

    unsigned short* hcur = HbA;
    unsigned short* hnxt = HbB;
    for (int l = 0; l < LAYERS; ++l) {
        gather_bf16<<<(N_NODES + 3) / 4, 256, 0, stream>>>(hcur, row_ptr, col_src, Sb);
        gru_fused<<<1564, 256, 0, stream>>>(Sb, hcur, WSb + (size_t)l * 768 * C, WHb,
                                            b_ih, b_hh, hnxt);
        unsigned short* t = hcur; hcur = hnxt; hnxt = t;
    }

    pool2<<<N_GRAPHS, 256, 0, stream>>>(hcur, batch, g);
    cls_kernel<<<N_GRAPHS, 128, 0, stream>>>(g, W1, b1, W2, b2, out);
}